// Round 5
// baseline (330.621 us; speedup 1.0000x reference)
//
#include <hip/hip_runtime.h>
#include <cstdint>
#include <cstddef>

constexpr int D = 256;       // embedding dim
constexpr int C = 128;       // num classes
constexpr float MARGIN = 1.0f;

typedef __attribute__((ext_vector_type(8))) short short8;
typedef __attribute__((ext_vector_type(4))) float f32x4;

// float -> bf16 bits (RNE)
__device__ inline unsigned f2bf(float x) {
    unsigned u = __float_as_uint(x);
    return (u + 0x7FFFu + ((u >> 16) & 1u)) >> 16;
}

// split x into bf16 hi + bf16 lo (x ~= hi + lo, exact to ~16 mantissa bits)
__device__ inline void cvt_split8(const float* xs, short8& h, short8& l) {
#pragma unroll
    for (int j = 0; j < 8; ++j) {
        float x = xs[j];
        unsigned hb = f2bf(x);
        h[j] = (short)hb;
        float hf = __uint_as_float(hb << 16);
        l[j] = (short)f2bf(x - hf);
    }
}

__device__ __forceinline__ void merge_top2(float& v1, int& i1, float& v2, int& i2,
                                           float w1, int j1, float w2, int j2)
{
    bool b = (w1 > v1) || (w1 == v1 && j1 < i1);
    float best_v = b ? w1 : v1; int best_i = b ? j1 : i1;
    float lose_v = b ? v1 : w1; int lose_i = b ? i1 : j1;
    float sec_v  = b ? w2 : v2; int sec_i  = b ? j2 : i2;
    bool c = (lose_v > sec_v) || (lose_v == sec_v && lose_i < sec_i);
    v1 = best_v; i1 = best_i;
    v2 = c ? lose_v : sec_v; i2 = c ? lose_i : sec_i;
}

// ---------------- K0: W fp32 -> bf16 hi ----------------
__global__ void k0_convW(const float* __restrict__ W, unsigned short* __restrict__ Whi)
{
    int i = blockIdx.x * 256 + threadIdx.x;     // 32768 total
    Whi[i] = (unsigned short)f2bf(W[i]);
}

// ---------------- K1: 2-term split-bf16 MFMA logits + top-2 + emb bf16 export ----------
// 256 thr = 4 waves: wave = (row-tile rt in {0,1}) x (class-half ch in {0,1}).
// Each wave: 16 rows x 64 classes, acc = 4 x f32x4 = 16 VGPRs. No big LDS, no staging.
// W-fragments read straight from global (64 KiB bf16, L1/L2-resident).
__launch_bounds__(256)
__global__ void k1_logits_top2(const float* __restrict__ emb,
                               const int*   __restrict__ labels,
                               const unsigned short* __restrict__ Whi,
                               const float* __restrict__ bias,
                               int*         __restrict__ target_neg,
                               unsigned short* __restrict__ embh,
                               int do_store)
{
    __shared__ float4 shTop[2][2][16];   // [rt][ch][row] = {v1, i1, v2, i2}
    const int tid = threadIdx.x;
    const int wid = tid >> 6, lane = tid & 63;
    const int rt = wid >> 1, ch = wid & 1;
    const int l15 = lane & 15, lq = lane >> 4;
    const long row0 = (long)blockIdx.x * 32 + rt * 16;

    f32x4 acc[4];
#pragma unroll
    for (int t = 0; t < 4; ++t) acc[t] = (f32x4){0.f, 0.f, 0.f, 0.f};

    const float* e0 = emb + (size_t)(row0 + l15) * D + 8 * lq;      // row (row0+l15), k base 8*lq
    char* eh0 = (char*)embh + (size_t)(row0 + l15) * 512 + 16 * lq;
    const char* wbase = (const char*)Whi + (ch * 64 + l15) * 512 + 16 * lq;

    float4 pa0 = *(const float4*)(e0);
    float4 pa1 = *(const float4*)(e0 + 4);

#pragma unroll
    for (int s = 0; s < 8; ++s) {                                   // k0 = 32*s
        float x0[8];
        *(float4*)&x0[0] = pa0; *(float4*)&x0[4] = pa1;
        if (s < 7) {
            pa0 = *(const float4*)(e0 + 32 * (s + 1));
            pa1 = *(const float4*)(e0 + 32 * (s + 1) + 4);
        }
        short8 ah, al;
        cvt_split8(x0, ah, al);
        if (do_store && ch == 0) *(short8*)(eh0 + 64 * s) = ah;
#pragma unroll
        for (int t = 0; t < 4; ++t) {
            short8 bh = *(const short8*)(wbase + t * (16 * 512) + 64 * s);
            acc[t] = __builtin_amdgcn_mfma_f32_16x16x32_bf16(ah, bh, acc[t], 0, 0, 0);
            acc[t] = __builtin_amdgcn_mfma_f32_16x16x32_bf16(al, bh, acc[t], 0, 0, 0);
        }
    }

    // epilogue: bias + per-row top-2 over this wave's 64 classes
    float bv[4];
#pragma unroll
    for (int t = 0; t < 4; ++t) bv[t] = bias[ch * 64 + 16 * t + l15];

    float v1[4], v2[4]; int i1[4], i2[4];   // reg slot -> row = lq*4 + reg
#pragma unroll
    for (int reg = 0; reg < 4; ++reg) {
        float a1 = -3.4e38f, a2 = -3.4e38f; int c1 = -1, c2 = -1;
#pragma unroll
        for (int t = 0; t < 4; ++t) {
            float v = acc[t][reg] + bv[t];
            int c = ch * 64 + 16 * t + l15;
            if (v > a1) { a2 = a1; c2 = c1; a1 = v; c1 = c; }
            else if (v > a2) { a2 = v; c2 = c; }
        }
        v1[reg] = a1; i1[reg] = c1; v2[reg] = a2; i2[reg] = c2;
    }
#pragma unroll
    for (int step = 1; step <= 8; step <<= 1) {
#pragma unroll
        for (int r = 0; r < 4; ++r) {
            float w1 = __shfl_xor(v1[r], step);
            int   j1 = __shfl_xor(i1[r], step);
            float w2 = __shfl_xor(v2[r], step);
            int   j2 = __shfl_xor(i2[r], step);
            merge_top2(v1[r], i1[r], v2[r], i2[r], w1, j1, w2, j2);
        }
    }
    if (l15 == 0) {
#pragma unroll
        for (int r = 0; r < 4; ++r)
            shTop[rt][ch][lq * 4 + r] =
                make_float4(v1[r], __int_as_float(i1[r]), v2[r], __int_as_float(i2[r]));
    }
    __syncthreads();
    if (tid < 32) {                      // row = blockIdx*32 + tid
        int rt2 = tid >> 4, rr = tid & 15;
        float4 h0 = shTop[rt2][0][rr];   // lower classes first -> tie priority preserved
        float4 h1 = shTop[rt2][1][rr];
        float m1 = h0.x; int a1 = __float_as_int(h0.y);
        float m2 = h0.z; int a2 = __float_as_int(h0.w);
        merge_top2(m1, a1, m2, a2, h1.x, __float_as_int(h1.y), h1.z, __float_as_int(h1.w));
        long grow = (long)blockIdx.x * 32 + tid;
        int lab = labels[grow];
        target_neg[grow] = (a1 == lab) ? a2 : a1;
    }
}

// ---------------- K2: full per-chunk histogram via 7 shared ballots ----------------
__global__ void k2_hist(const int* __restrict__ labels, int* __restrict__ hist)
{
    const int chunk = blockIdx.x * 4 + (threadIdx.x >> 6);
    const int lane = threadIdx.x & 63;
    const int lab = labels[chunk * 64 + lane];
    unsigned long long bal[7];
#pragma unroll
    for (int b = 0; b < 7; ++b) bal[b] = __ballot((lab >> b) & 1);
#pragma unroll
    for (int h = 0; h < 2; ++h) {
        const int c = lane + 64 * h;
        unsigned long long m = ~0ull;
#pragma unroll
        for (int b = 0; b < 7; ++b) m &= ((c >> b) & 1) ? bal[b] : ~bal[b];
        hist[chunk * C + c] = __popcll(m);
    }
}

// ---------------- K3: per-class exclusive scan over chunks ----------------
__global__ void k3_scan(int* __restrict__ hist, int* __restrict__ counts, int nchunk)
{
    const int c = blockIdx.x;
    const int tid = threadIdx.x;
    const int per = nchunk / 256;           // 8 for B=131072
    int v[8];
    int s = 0;
#pragma unroll
    for (int j = 0; j < 8; ++j) {
        int x = (j < per) ? hist[(tid * per + j) * C + c] : 0;
        v[j] = s; s += x;
    }
    __shared__ int sm[256];
    sm[tid] = s;
    __syncthreads();
    for (int off = 1; off < 256; off <<= 1) {
        int x = (tid >= off) ? sm[tid - off] : 0;
        __syncthreads();
        sm[tid] += x;
        __syncthreads();
    }
    const int excl = sm[tid] - s;
#pragma unroll
    for (int j = 0; j < 8; ++j)
        if (j < per) hist[(tid * per + j) * C + c] = excl + v[j];
    if (tid == 255) counts[c] = sm[255];
}

// ---------------- K3b: class starts via wave shuffle scan ----------------
__global__ void k3b_start(const int* __restrict__ counts, int* __restrict__ class_start)
{
    const int l = threadIdx.x;               // 0..63
    int c0 = counts[l], c1 = counts[l + 64];
    int x = c0, y = c1;
#pragma unroll
    for (int off = 1; off <= 32; off <<= 1) {
        int vx = __shfl_up(x, off);
        int vy = __shfl_up(y, off);
        if (l >= off) { x += vx; y += vy; }
    }
    int tot0 = __shfl(x, 63);
    class_start[l] = x - c0;
    class_start[64 + l] = tot0 + y - c1;
}

// ---------------- K4: scatter stable order + rank ----------------
__global__ void k4_scatter(const int* __restrict__ labels, const int* __restrict__ hist,
                           const int* __restrict__ class_start,
                           int* __restrict__ order, int* __restrict__ rankArr)
{
    const int chunk = blockIdx.x * 4 + (threadIdx.x >> 6);
    const int lane = threadIdx.x & 63;
    const int i = chunk * 64 + lane;
    const int lab = labels[i];
    unsigned long long m = ~0ull;
#pragma unroll
    for (int b = 0; b < 7; ++b) {
        unsigned long long bal = __ballot((lab >> b) & 1);
        m &= ((lab >> b) & 1) ? bal : ~bal;
    }
    const int prefix = __popcll(m & ((1ull << lane) - 1ull));
    const int rank = hist[chunk * C + lab] + prefix;
    order[class_start[lab] + rank] = i;
    rankArr[i] = rank;
}

// ---------------- K5a: sample pos/neg indices (1 thread / row) ----------------
__global__ void k5a_sample(const int* __restrict__ labels, const int* __restrict__ target_neg,
                           const int* __restrict__ counts, const int* __restrict__ class_start,
                           const int* __restrict__ order, const int* __restrict__ rankArr,
                           const int* __restrict__ r_pos, const int* __restrict__ r_neg,
                           int* __restrict__ pos_idx, int* __restrict__ neg_idx, int B)
{
    const int i = blockIdx.x * blockDim.x + threadIdx.x;
    if (i >= B) return;
    const int lab = labels[i];
    const int tn = target_neg[i];
    const int n_pos = counts[lab] - 1;
    const int n_neg = counts[tn];
    int pr = r_pos[i] % max(n_pos, 1);
    pr += (pr >= rankArr[i]) ? 1 : 0;
    int ppos = class_start[lab] + pr; if (ppos > B - 1) ppos = B - 1;
    const int pidx = order[ppos];
    int nr = r_neg[i] % max(n_neg, 1);
    int npos = class_start[tn] + nr; if (npos > B - 1) npos = B - 1;
    const int nidx = order[npos];
    const bool valid = (n_pos > 0) && (n_neg > 0);
    pos_idx[i] = valid ? pidx : -1;
    neg_idx[i] = nidx;
}

// ---------------- K56: distances + hinge, 16 lanes/row, 2 rows in flight ----------------
__device__ inline void acc_pair(unsigned a, unsigned b, float& s) {
    float d0 = __uint_as_float(a << 16)         - __uint_as_float(b << 16);
    float d1 = __uint_as_float(a & 0xFFFF0000u) - __uint_as_float(b & 0xFFFF0000u);
    s = fmaf(d0, d0, s);
    s = fmaf(d1, d1, s);
}
__device__ inline void acc16(uint4 a, uint4 b, float& s) {
    acc_pair(a.x, b.x, s); acc_pair(a.y, b.y, s);
    acc_pair(a.z, b.z, s); acc_pair(a.w, b.w, s);
}

__launch_bounds__(256)
__global__ void k56_dist(const unsigned short* __restrict__ embh,
                         const float* __restrict__ embf,
                         const int* __restrict__ pos_idx, const int* __restrict__ neg_idx,
                         float* __restrict__ ploss, int* __restrict__ pcnt,
                         int B, int use_bf16)
{
    const int lane = threadIdx.x & 63;
    const int wid = threadIdx.x >> 6;
    const int l16 = threadIdx.x & 15;
    const int g = (blockIdx.x * blockDim.x + threadIdx.x) >> 4;
    const int ngroups = (gridDim.x * blockDim.x) >> 4;
    float lsum = 0.0f;
    int lcnt = 0;
    for (int row = g * 2; row < B; row += ngroups * 2) {
        const int r0 = row, r1 = row + 1;
        const int p0 = pos_idx[r0], n0 = neg_idx[r0];
        const bool has1 = (r1 < B);
        const int p1 = has1 ? pos_idx[r1] : -1;
        const int n1 = has1 ? neg_idx[r1] : 0;
        float dp0 = 0.f, dn0 = 0.f, dp1 = 0.f, dn1 = 0.f;
        if (use_bf16) {
            uint4 a00, a01, pv00, pv01, nv00, nv01;
            uint4 a10, a11, pv10, pv11, nv10, nv11;
            if (p0 >= 0) {
                const uint4* a4 = (const uint4*)(embh + (size_t)r0 * D);
                const uint4* p4 = (const uint4*)(embh + (size_t)p0 * D);
                const uint4* n4 = (const uint4*)(embh + (size_t)n0 * D);
                a00 = a4[2 * l16]; a01 = a4[2 * l16 + 1];
                pv00 = p4[2 * l16]; pv01 = p4[2 * l16 + 1];
                nv00 = n4[2 * l16]; nv01 = n4[2 * l16 + 1];
            }
            if (p1 >= 0) {
                const uint4* a4 = (const uint4*)(embh + (size_t)r1 * D);
                const uint4* p4 = (const uint4*)(embh + (size_t)p1 * D);
                const uint4* n4 = (const uint4*)(embh + (size_t)n1 * D);
                a10 = a4[2 * l16]; a11 = a4[2 * l16 + 1];
                pv10 = p4[2 * l16]; pv11 = p4[2 * l16 + 1];
                nv10 = n4[2 * l16]; nv11 = n4[2 * l16 + 1];
            }
            if (p0 >= 0) {
                acc16(a00, pv00, dp0); acc16(a01, pv01, dp0);
                acc16(a00, nv00, dn0); acc16(a01, nv01, dn0);
            }
            if (p1 >= 0) {
                acc16(a10, pv10, dp1); acc16(a11, pv11, dp1);
                acc16(a10, nv10, dn1); acc16(a11, nv11, dn1);
            }
        } else {
            if (p0 >= 0) {
                const float4* a4 = (const float4*)(embf + (size_t)r0 * D);
                const float4* p4 = (const float4*)(embf + (size_t)p0 * D);
                const float4* n4 = (const float4*)(embf + (size_t)n0 * D);
#pragma unroll
                for (int j = 0; j < 4; ++j) {
                    float4 a = a4[l16 + 16 * j], bp = p4[l16 + 16 * j], bn = n4[l16 + 16 * j];
                    float dx;
                    dx = a.x - bp.x; dp0 = fmaf(dx, dx, dp0);
                    dx = a.y - bp.y; dp0 = fmaf(dx, dx, dp0);
                    dx = a.z - bp.z; dp0 = fmaf(dx, dx, dp0);
                    dx = a.w - bp.w; dp0 = fmaf(dx, dx, dp0);
                    dx = a.x - bn.x; dn0 = fmaf(dx, dx, dn0);
                    dx = a.y - bn.y; dn0 = fmaf(dx, dx, dn0);
                    dx = a.z - bn.z; dn0 = fmaf(dx, dx, dn0);
                    dx = a.w - bn.w; dn0 = fmaf(dx, dx, dn0);
                }
            }
            if (p1 >= 0) {
                const float4* a4 = (const float4*)(embf + (size_t)r1 * D);
                const float4* p4 = (const float4*)(embf + (size_t)p1 * D);
                const float4* n4 = (const float4*)(embf + (size_t)n1 * D);
#pragma unroll
                for (int j = 0; j < 4; ++j) {
                    float4 a = a4[l16 + 16 * j], bp = p4[l16 + 16 * j], bn = n4[l16 + 16 * j];
                    float dx;
                    dx = a.x - bp.x; dp1 = fmaf(dx, dx, dp1);
                    dx = a.y - bp.y; dp1 = fmaf(dx, dx, dp1);
                    dx = a.z - bp.z; dp1 = fmaf(dx, dx, dp1);
                    dx = a.w - bp.w; dp1 = fmaf(dx, dx, dp1);
                    dx = a.x - bn.x; dn1 = fmaf(dx, dx, dn1);
                    dx = a.y - bn.y; dn1 = fmaf(dx, dx, dn1);
                    dx = a.z - bn.z; dn1 = fmaf(dx, dx, dn1);
                    dx = a.w - bn.w; dn1 = fmaf(dx, dx, dn1);
                }
            }
        }
#pragma unroll
        for (int off = 8; off >= 1; off >>= 1) {
            dp0 += __shfl_xor(dp0, off); dn0 += __shfl_xor(dn0, off);
            dp1 += __shfl_xor(dp1, off); dn1 += __shfl_xor(dn1, off);
        }
        if (l16 == 0) {
            if (p0 >= 0) { lsum += fmaxf(sqrtf(dp0) - sqrtf(dn0) + MARGIN, 0.0f); lcnt += 1; }
            if (p1 >= 0) { lsum += fmaxf(sqrtf(dp1) - sqrtf(dn1) + MARGIN, 0.0f); lcnt += 1; }
        }
    }
    lsum += __shfl_xor(lsum, 16); lcnt += __shfl_xor(lcnt, 16);
    lsum += __shfl_xor(lsum, 32); lcnt += __shfl_xor(lcnt, 32);
    __shared__ float sl[4];
    __shared__ int   sc[4];
    if (lane == 0) { sl[wid] = lsum; sc[wid] = lcnt; }
    __syncthreads();
    if (threadIdx.x == 0) {
        ploss[blockIdx.x] = sl[0] + sl[1] + sl[2] + sl[3];
        pcnt[blockIdx.x]  = sc[0] + sc[1] + sc[2] + sc[3];
    }
}

// ---------------- K6: final reduce + divide ----------------
__global__ void k6_final(const float* __restrict__ ploss, const int* __restrict__ pcnt,
                         float* __restrict__ out, int nb)
{
    const int tid = threadIdx.x;
    float s = 0.0f; int c = 0;
    for (int j = tid; j < nb; j += 256) { s += ploss[j]; c += pcnt[j]; }
    __shared__ float sf[256];
    __shared__ int   si[256];
    sf[tid] = s; si[tid] = c;
    __syncthreads();
    for (int off = 128; off >= 1; off >>= 1) {
        if (tid < off) { sf[tid] += sf[tid + off]; si[tid] += si[tid + off]; }
        __syncthreads();
    }
    if (tid == 0) out[0] = sf[0] / (float)max(si[0], 1);
}

extern "C" void kernel_launch(void* const* d_in, const int* in_sizes, int n_in,
                              void* d_out, int out_size, void* d_ws, size_t ws_size,
                              hipStream_t stream) {
    const float* emb    = (const float*)d_in[0];
    const int*   labels = (const int*)d_in[1];
    const float* W      = (const float*)d_in[2];
    const float* bias   = (const float*)d_in[3];
    const int*   r_pos  = (const int*)d_in[4];
    const int*   r_neg  = (const int*)d_in[5];
    float* out = (float*)d_out;

    const int B = in_sizes[1];
    const int nchunk = B / 64;
    const int NB5 = 4096;

    size_t off = 0;
    auto alloc = [&](size_t bytes) -> void* {
        void* p = (char*)d_ws + off;
        off += (bytes + 255) & ~(size_t)255;
        return p;
    };
    int* hist        = (int*)alloc((size_t)C * nchunk * 4);
    int* counts      = (int*)alloc(C * 4);
    int* class_start = (int*)alloc(C * 4);
    int* target_neg  = (int*)alloc((size_t)B * 4);
    int* rankArr     = (int*)alloc((size_t)B * 4);
    int* order       = (int*)alloc((size_t)B * 4);
    int* pos_idx     = (int*)alloc((size_t)B * 4);
    int* neg_idx     = (int*)alloc((size_t)B * 4);
    float* ploss     = (float*)alloc((size_t)NB5 * 4);
    int* pcnt        = (int*)alloc((size_t)NB5 * 4);
    unsigned short* Whi = (unsigned short*)alloc((size_t)C * D * 2);
    if (off > ws_size) return;   // core scratch missing -> visible failure

    // optional bf16 emb mirror (large); fall back to fp32 distances if ws too small
    unsigned short* embh = (unsigned short*)alloc((size_t)B * D * 2);
    const int use_bf16 = (off <= ws_size) ? 1 : 0;

    k0_convW<<<(C * D) / 256, 256, 0, stream>>>(W, Whi);
    k1_logits_top2<<<B / 32, 256, 0, stream>>>(emb, labels, Whi, bias, target_neg,
                                               use_bf16 ? embh : (unsigned short*)target_neg,
                                               use_bf16);
    k2_hist<<<nchunk / 4, 256, 0, stream>>>(labels, hist);
    k3_scan<<<C, 256, 0, stream>>>(hist, counts, nchunk);
    k3b_start<<<1, 64, 0, stream>>>(counts, class_start);
    k4_scatter<<<nchunk / 4, 256, 0, stream>>>(labels, hist, class_start, order, rankArr);
    k5a_sample<<<(B + 255) / 256, 256, 0, stream>>>(labels, target_neg, counts, class_start,
                                                    order, rankArr, r_pos, r_neg,
                                                    pos_idx, neg_idx, B);
    k56_dist<<<NB5, 256, 0, stream>>>(embh, emb, pos_idx, neg_idx, ploss, pcnt, B, use_bf16);
    k6_final<<<1, 256, 0, stream>>>(ploss, pcnt, out, NB5);
}

// Round 6
// 279.606 us; speedup vs baseline: 1.1825x; 1.1825x over previous
//
#include <hip/hip_runtime.h>
#include <hip/hip_bf16.h>
#include <cstdint>
#include <cstddef>

constexpr int D = 256;       // embedding dim
constexpr int C = 128;       // num classes
constexpr float MARGIN = 1.0f;

typedef __attribute__((ext_vector_type(8))) short short8;
typedef __attribute__((ext_vector_type(4))) float f32x4;

__device__ inline unsigned short f2bf16(float x) {
    union { __hip_bfloat16 b; unsigned short u; } cv;
    cv.b = __float2bfloat16(x);
    return cv.u;
}

__device__ __forceinline__ void merge_top2(float& v1, int& i1, float& v2, int& i2,
                                           float w1, int j1, float w2, int j2)
{
    bool b = (w1 > v1) || (w1 == v1 && j1 < i1);
    float best_v = b ? w1 : v1; int best_i = b ? j1 : i1;
    float lose_v = b ? v1 : w1; int lose_i = b ? i1 : j1;
    float sec_v  = b ? w2 : v2; int sec_i  = b ? j2 : i2;
    bool c = (lose_v > sec_v) || (lose_v == sec_v && lose_i < sec_i);
    v1 = best_v; i1 = best_i;
    v2 = c ? lose_v : sec_v; i2 = c ? lose_i : sec_i;
}

// ---------------- KCONV: emb fp32 -> bf16 (streaming, BW-bound) ----------------
__launch_bounds__(256)
__global__ void kconv(const float* __restrict__ emb, unsigned short* __restrict__ embh)
{
    const size_t i = (size_t)blockIdx.x * 256 + threadIdx.x;   // one short8 per thread
    const float4* s = (const float4*)emb + 2 * i;
    float4 f0 = s[0], f1 = s[1];
    short8 h;
    h[0] = (short)f2bf16(f0.x); h[1] = (short)f2bf16(f0.y);
    h[2] = (short)f2bf16(f0.z); h[3] = (short)f2bf16(f0.w);
    h[4] = (short)f2bf16(f1.x); h[5] = (short)f2bf16(f1.y);
    h[6] = (short)f2bf16(f1.z); h[7] = (short)f2bf16(f1.w);
    *((short8*)embh + i) = h;
}

// ---------------- K1: bf16 MFMA logits + top-2 (reads pre-converted embh) --------
// 512 thr = 8 waves, 256 rows/block. LDS: W bf16 64KB swizzled -> 2 blocks/CU.
__launch_bounds__(512, 4)
__global__ void k1_logits_top2(const unsigned short* __restrict__ embh,
                               const int*   __restrict__ labels,
                               const float* __restrict__ W,
                               const float* __restrict__ bias,
                               int*         __restrict__ target_neg)
{
    __shared__ char ldsW[C * 512];       // 128 class rows x 256 bf16, swizzled
    __shared__ float ldsBias[C];
    const int tid = threadIdx.x;

    // stage + convert W (fp32 -> bf16), XOR-swizzled 16B chunks
#pragma unroll
    for (int c = tid; c < 4096; c += 512) {
        int n = c >> 5, slot = c & 31;
        const float* src = W + n * 256 + slot * 8;
        float4 f0 = *(const float4*)src;
        float4 f1 = *(const float4*)(src + 4);
        short8 h;
        h[0] = (short)f2bf16(f0.x); h[1] = (short)f2bf16(f0.y);
        h[2] = (short)f2bf16(f0.z); h[3] = (short)f2bf16(f0.w);
        h[4] = (short)f2bf16(f1.x); h[5] = (short)f2bf16(f1.y);
        h[6] = (short)f2bf16(f1.z); h[7] = (short)f2bf16(f1.w);
        int dst = (n * 512 + slot * 16) ^ ((n & 7) << 4);
        *(short8*)(ldsW + dst) = h;
    }
    if (tid < C) ldsBias[tid] = bias[tid];
    __syncthreads();

    const int wid = tid >> 6, lane = tid & 63;
    const int l15 = lane & 15, lq = lane >> 4;
    const long row0 = (long)blockIdx.x * 256 + wid * 32;

    f32x4 acc[2][8];
#pragma unroll
    for (int rt = 0; rt < 2; ++rt)
#pragma unroll
        for (int t = 0; t < 8; ++t) acc[rt][t] = (f32x4){0.f, 0.f, 0.f, 0.f};

    const char* a0p = (const char*)embh + (size_t)(row0 + l15) * 512 + 16 * lq;
    const char* a1p = a0p + (size_t)16 * 512;
    const int xm = (l15 & 7) << 4;

#pragma unroll
    for (int s = 0; s < 8; ++s) {                                 // k0 = 32*s
        short8 ah0 = *(const short8*)(a0p + 64 * s);
        short8 ah1 = *(const short8*)(a1p + 64 * s);
#pragma unroll
        for (int t = 0; t < 8; ++t) {
            int addr = ((16 * t + l15) * 512 + 64 * s + 16 * lq) ^ xm;
            short8 bh = *(const short8*)(ldsW + addr);
            acc[0][t] = __builtin_amdgcn_mfma_f32_16x16x32_bf16(ah0, bh, acc[0][t], 0, 0, 0);
            acc[1][t] = __builtin_amdgcn_mfma_f32_16x16x32_bf16(ah1, bh, acc[1][t], 0, 0, 0);
        }
    }

    // epilogue: bias + per-row top-2 (col = class = 16t+l15; row = rt*16 + lq*4 + reg)
    float bv[8];
#pragma unroll
    for (int t = 0; t < 8; ++t) bv[t] = ldsBias[16 * t + l15];

    float v1[8], v2[8]; int i1[8], i2[8];
#pragma unroll
    for (int rt = 0; rt < 2; ++rt)
#pragma unroll
        for (int reg = 0; reg < 4; ++reg) {
            int sIdx = rt * 4 + reg;
            float a1 = -3.4e38f, a2 = -3.4e38f; int c1 = -1, c2 = -1;
#pragma unroll
            for (int t = 0; t < 8; ++t) {
                float v = acc[rt][t][reg] + bv[t];
                int c = 16 * t + l15;
                if (v > a1) { a2 = a1; c2 = c1; a1 = v; c1 = c; }
                else if (v > a2) { a2 = v; c2 = c; }
            }
            v1[sIdx] = a1; i1[sIdx] = c1; v2[sIdx] = a2; i2[sIdx] = c2;
        }
#pragma unroll
    for (int step = 1; step <= 8; step <<= 1) {
#pragma unroll
        for (int sIdx = 0; sIdx < 8; ++sIdx) {
            float w1 = __shfl_xor(v1[sIdx], step);
            int   j1 = __shfl_xor(i1[sIdx], step);
            float w2 = __shfl_xor(v2[sIdx], step);
            int   j2 = __shfl_xor(i2[sIdx], step);
            merge_top2(v1[sIdx], i1[sIdx], v2[sIdx], i2[sIdx], w1, j1, w2, j2);
        }
    }
    if (l15 == 0) {
#pragma unroll
        for (int rt = 0; rt < 2; ++rt)
#pragma unroll
            for (int reg = 0; reg < 4; ++reg) {
                int sIdx = rt * 4 + reg;
                long grow = row0 + rt * 16 + lq * 4 + reg;
                int lab = labels[grow];
                target_neg[grow] = (i1[sIdx] == lab) ? i2[sIdx] : i1[sIdx];
            }
    }
}

// ---------------- K2: full per-chunk histogram via 7 shared ballots ----------------
__global__ void k2_hist(const int* __restrict__ labels, int* __restrict__ hist)
{
    const int chunk = blockIdx.x * 4 + (threadIdx.x >> 6);
    const int lane = threadIdx.x & 63;
    const int lab = labels[chunk * 64 + lane];
    unsigned long long bal[7];
#pragma unroll
    for (int b = 0; b < 7; ++b) bal[b] = __ballot((lab >> b) & 1);
#pragma unroll
    for (int h = 0; h < 2; ++h) {
        const int c = lane + 64 * h;
        unsigned long long m = ~0ull;
#pragma unroll
        for (int b = 0; b < 7; ++b) m &= ((c >> b) & 1) ? bal[b] : ~bal[b];
        hist[chunk * C + c] = __popcll(m);
    }
}

// ---------------- K3: per-class exclusive scan over chunks ----------------
__global__ void k3_scan(int* __restrict__ hist, int* __restrict__ counts, int nchunk)
{
    const int c = blockIdx.x;
    const int tid = threadIdx.x;
    const int per = nchunk / 256;           // 8 for B=131072
    int v[8];
    int s = 0;
#pragma unroll
    for (int j = 0; j < 8; ++j) {
        int x = (j < per) ? hist[(tid * per + j) * C + c] : 0;
        v[j] = s; s += x;
    }
    __shared__ int sm[256];
    sm[tid] = s;
    __syncthreads();
    for (int off = 1; off < 256; off <<= 1) {
        int x = (tid >= off) ? sm[tid - off] : 0;
        __syncthreads();
        sm[tid] += x;
        __syncthreads();
    }
    const int excl = sm[tid] - s;
#pragma unroll
    for (int j = 0; j < 8; ++j)
        if (j < per) hist[(tid * per + j) * C + c] = excl + v[j];
    if (tid == 255) counts[c] = sm[255];
}

// ---------------- K3b: class starts via wave shuffle scan ----------------
__global__ void k3b_start(const int* __restrict__ counts, int* __restrict__ class_start)
{
    const int l = threadIdx.x;               // 0..63
    int c0 = counts[l], c1 = counts[l + 64];
    int x = c0, y = c1;
#pragma unroll
    for (int off = 1; off <= 32; off <<= 1) {
        int vx = __shfl_up(x, off);
        int vy = __shfl_up(y, off);
        if (l >= off) { x += vx; y += vy; }
    }
    int tot0 = __shfl(x, 63);
    class_start[l] = x - c0;
    class_start[64 + l] = tot0 + y - c1;
}

// ---------------- K4: scatter stable order + rank ----------------
__global__ void k4_scatter(const int* __restrict__ labels, const int* __restrict__ hist,
                           const int* __restrict__ class_start,
                           int* __restrict__ order, int* __restrict__ rankArr)
{
    const int chunk = blockIdx.x * 4 + (threadIdx.x >> 6);
    const int lane = threadIdx.x & 63;
    const int i = chunk * 64 + lane;
    const int lab = labels[i];
    unsigned long long m = ~0ull;
#pragma unroll
    for (int b = 0; b < 7; ++b) {
        unsigned long long bal = __ballot((lab >> b) & 1);
        m &= ((lab >> b) & 1) ? bal : ~bal;
    }
    const int prefix = __popcll(m & ((1ull << lane) - 1ull));
    const int rank = hist[chunk * C + lab] + prefix;
    order[class_start[lab] + rank] = i;
    rankArr[i] = rank;
}

// ---------------- K5a: sample pos/neg indices (1 thread / row) ----------------
__global__ void k5a_sample(const int* __restrict__ labels, const int* __restrict__ target_neg,
                           const int* __restrict__ counts, const int* __restrict__ class_start,
                           const int* __restrict__ order, const int* __restrict__ rankArr,
                           const int* __restrict__ r_pos, const int* __restrict__ r_neg,
                           int* __restrict__ pos_idx, int* __restrict__ neg_idx, int B)
{
    const int i = blockIdx.x * blockDim.x + threadIdx.x;
    if (i >= B) return;
    const int lab = labels[i];
    const int tn = target_neg[i];
    const int n_pos = counts[lab] - 1;
    const int n_neg = counts[tn];
    int pr = r_pos[i] % max(n_pos, 1);
    pr += (pr >= rankArr[i]) ? 1 : 0;
    int ppos = class_start[lab] + pr; if (ppos > B - 1) ppos = B - 1;
    const int pidx = order[ppos];
    int nr = r_neg[i] % max(n_neg, 1);
    int npos = class_start[tn] + nr; if (npos > B - 1) npos = B - 1;
    const int nidx = order[npos];
    const bool valid = (n_pos > 0) && (n_neg > 0);
    pos_idx[i] = valid ? pidx : -1;
    neg_idx[i] = nidx;
}

// ---------------- K56: distances + hinge, 16 lanes/row, 4 rows unrolled ----------------
__device__ inline void acc_pair(unsigned a, unsigned b, float& s) {
    float d0 = __uint_as_float(a << 16)         - __uint_as_float(b << 16);
    float d1 = __uint_as_float(a & 0xFFFF0000u) - __uint_as_float(b & 0xFFFF0000u);
    s = fmaf(d0, d0, s);
    s = fmaf(d1, d1, s);
}
__device__ inline void acc16(uint4 a, uint4 b, float& s) {
    acc_pair(a.x, b.x, s); acc_pair(a.y, b.y, s);
    acc_pair(a.z, b.z, s); acc_pair(a.w, b.w, s);
}

__launch_bounds__(256)
__global__ void k56_dist(const unsigned short* __restrict__ embh,
                         const int* __restrict__ pos_idx, const int* __restrict__ neg_idx,
                         float* __restrict__ ploss, int* __restrict__ pcnt, int B)
{
    const int lane = threadIdx.x & 63;
    const int wid = threadIdx.x >> 6;
    const int l16 = threadIdx.x & 15;
    const int g = (blockIdx.x * blockDim.x + threadIdx.x) >> 4;   // 32768 groups
    float lsum = 0.0f;
    int lcnt = 0;

    int pI[4], nI[4];
    uint4 av0[4], av1[4], pv0[4], pv1[4], nv0[4], nv1[4];
#pragma unroll
    for (int r = 0; r < 4; ++r) {
        const int row = g * 4 + r;
        pI[r] = pos_idx[row]; nI[r] = neg_idx[row];
    }
#pragma unroll
    for (int r = 0; r < 4; ++r) {
        const int row = g * 4 + r;
        if (pI[r] >= 0) {
            const uint4* a4 = (const uint4*)(embh + (size_t)row   * D);
            const uint4* p4 = (const uint4*)(embh + (size_t)pI[r] * D);
            const uint4* n4 = (const uint4*)(embh + (size_t)nI[r] * D);
            av0[r] = a4[2 * l16]; av1[r] = a4[2 * l16 + 1];
            pv0[r] = p4[2 * l16]; pv1[r] = p4[2 * l16 + 1];
            nv0[r] = n4[2 * l16]; nv1[r] = n4[2 * l16 + 1];
        }
    }
    float dp[4], dn[4];
#pragma unroll
    for (int r = 0; r < 4; ++r) {
        dp[r] = 0.f; dn[r] = 0.f;
        if (pI[r] >= 0) {
            acc16(av0[r], pv0[r], dp[r]); acc16(av1[r], pv1[r], dp[r]);
            acc16(av0[r], nv0[r], dn[r]); acc16(av1[r], nv1[r], dn[r]);
        }
    }
#pragma unroll
    for (int off = 8; off >= 1; off >>= 1)
#pragma unroll
        for (int r = 0; r < 4; ++r) {
            dp[r] += __shfl_xor(dp[r], off);
            dn[r] += __shfl_xor(dn[r], off);
        }
    if (l16 == 0) {
#pragma unroll
        for (int r = 0; r < 4; ++r)
            if (pI[r] >= 0) {
                lsum += fmaxf(sqrtf(dp[r]) - sqrtf(dn[r]) + MARGIN, 0.0f);
                lcnt += 1;
            }
    }
    lsum += __shfl_xor(lsum, 16); lcnt += __shfl_xor(lcnt, 16);
    lsum += __shfl_xor(lsum, 32); lcnt += __shfl_xor(lcnt, 32);
    __shared__ float sl[4];
    __shared__ int   sc[4];
    if (lane == 0) { sl[wid] = lsum; sc[wid] = lcnt; }
    __syncthreads();
    if (threadIdx.x == 0) {
        ploss[blockIdx.x] = sl[0] + sl[1] + sl[2] + sl[3];
        pcnt[blockIdx.x]  = sc[0] + sc[1] + sc[2] + sc[3];
    }
}

// ---------------- K6: final reduce + divide ----------------
__global__ void k6_final(const float* __restrict__ ploss, const int* __restrict__ pcnt,
                         float* __restrict__ out, int nb)
{
    const int tid = threadIdx.x;
    float s = 0.0f; int c = 0;
    for (int j = tid; j < nb; j += 256) { s += ploss[j]; c += pcnt[j]; }
    __shared__ float sf[256];
    __shared__ int   si[256];
    sf[tid] = s; si[tid] = c;
    __syncthreads();
    for (int off = 128; off >= 1; off >>= 1) {
        if (tid < off) { sf[tid] += sf[tid + off]; si[tid] += si[tid + off]; }
        __syncthreads();
    }
    if (tid == 0) out[0] = sf[0] / (float)max(si[0], 1);
}

extern "C" void kernel_launch(void* const* d_in, const int* in_sizes, int n_in,
                              void* d_out, int out_size, void* d_ws, size_t ws_size,
                              hipStream_t stream) {
    const float* emb    = (const float*)d_in[0];
    const int*   labels = (const int*)d_in[1];
    const float* W      = (const float*)d_in[2];
    const float* bias   = (const float*)d_in[3];
    const int*   r_pos  = (const int*)d_in[4];
    const int*   r_neg  = (const int*)d_in[5];
    float* out = (float*)d_out;

    const int B = in_sizes[1];
    const int nchunk = B / 64;
    const int NB5 = 2048;                 // k56 blocks: 2048*256/16*4 = B rows

    size_t off = 0;
    auto alloc = [&](size_t bytes) -> void* {
        void* p = (char*)d_ws + off;
        off += (bytes + 255) & ~(size_t)255;
        return p;
    };
    int* hist        = (int*)alloc((size_t)C * nchunk * 4);
    int* counts      = (int*)alloc(C * 4);
    int* class_start = (int*)alloc(C * 4);
    int* target_neg  = (int*)alloc((size_t)B * 4);
    int* rankArr     = (int*)alloc((size_t)B * 4);
    int* order       = (int*)alloc((size_t)B * 4);
    int* pos_idx     = (int*)alloc((size_t)B * 4);
    int* neg_idx     = (int*)alloc((size_t)B * 4);
    float* ploss     = (float*)alloc((size_t)NB5 * 4);
    int* pcnt        = (int*)alloc((size_t)NB5 * 4);
    unsigned short* embh = (unsigned short*)alloc((size_t)B * D * 2);
    if (off > ws_size) return;   // insufficient workspace -> visible failure

    kconv<<<(B * (D / 8)) / 256, 256, 0, stream>>>(emb, embh);
    k1_logits_top2<<<B / 256, 512, 0, stream>>>(embh, labels, W, bias, target_neg);
    k2_hist<<<nchunk / 4, 256, 0, stream>>>(labels, hist);
    k3_scan<<<C, 256, 0, stream>>>(hist, counts, nchunk);
    k3b_start<<<1, 64, 0, stream>>>(counts, class_start);
    k4_scatter<<<nchunk / 4, 256, 0, stream>>>(labels, hist, class_start, order, rankArr);
    k5a_sample<<<(B + 255) / 256, 256, 0, stream>>>(labels, target_neg, counts, class_start,
                                                    order, rankArr, r_pos, r_neg,
                                                    pos_idx, neg_idx, B);
    k56_dist<<<NB5, 256, 0, stream>>>(embh, pos_idx, neg_idx, ploss, pcnt, B);
    k6_final<<<1, 256, 0, stream>>>(ploss, pcnt, out, NB5);
}